// Round 14
// baseline (273.318 us; speedup 1.0000x reference)
//
#include <hip/hip_runtime.h>
#include <hip/hip_bf16.h>

typedef __attribute__((ext_vector_type(8))) short short8;
typedef __attribute__((ext_vector_type(4))) short short4v;
typedef __attribute__((ext_vector_type(4))) float floatx4;
typedef __attribute__((ext_vector_type(16))) float floatx16;

#define DI __device__ __forceinline__

// Problem constants
constexpr int B_ = 2, N_ = 2048, H_ = 16, DK_ = 128, DV_ = 128, E_ = 2048;
constexpr int M_ = B_ * N_;          // 4096 token rows
constexpr int NCAT_ = 4 * E_;        // 8192 = q|k|v|g concat
constexpr int CH_ = 128;             // chunk length
constexpr int NC_ = N_ / CH_;        // 16 chunks
constexpr float KSCALE = 0.08838834764831845f; // 1/sqrt(128)

// Workspace layout (bytes)
constexpr long OFF_XB   = 0;                    // 16MB  bf16 x      (reused as RG after GEMM1)
constexpr long OFF_WCAT = 16777216;             // 32MB  bf16 Wq|Wk|Wv|Wg  (reused as MS bf16 after GEMM1)
constexpr long OFF_WOB  = 50331648;             // 8MB   bf16 Wo
constexpr long OFF_BCAT = 58720256;             // 32KB  f32 concat bias
constexpr long OFF_Y    = 58753024;             // 64MB  bf16 [4096][8192] qd|kd|v|silu(g)
constexpr long OFF_VT   = 142639104;            // 16MB  bf16 Vt  [b][h][dv][t]
constexpr long OFF_SCB  = 159416320;            // 16MB  bf16 per-chunk start states [bh][c][dv][dk]

DI unsigned short f2bf(float f){
  unsigned u = __float_as_uint(f);
  u += 0x7fffu + ((u >> 16) & 1u);
  return (unsigned short)(u >> 16);
}
DI float bf2f(unsigned short s){ return __uint_as_float(((unsigned)s) << 16); }

DI float fexp2(float x){ return __builtin_amdgcn_exp2f(x); }   // v_exp_f32: 2^x
DI float flog2(float x){ return __builtin_amdgcn_logf(x); }    // v_log_f32: log2(x)

DI void gload_lds16(const void* g, void* l){
  __builtin_amdgcn_global_load_lds(
      (const __attribute__((address_space(1))) unsigned int*)g,
      (__attribute__((address_space(3))) unsigned int*)l, 16, 0, 0);
}

// ---------------- fused prep: all f32->bf16 casts + bias concat ----------------
__global__ void k_castall(const float* __restrict__ x,
                          const float* __restrict__ Wq, const float* __restrict__ Wk,
                          const float* __restrict__ Wv, const float* __restrict__ Wg,
                          const float* __restrict__ Wo,
                          const float* __restrict__ bq, const float* __restrict__ bk,
                          const float* __restrict__ bv, const float* __restrict__ bg,
                          unsigned short* __restrict__ xb, unsigned short* __restrict__ Wcat,
                          unsigned short* __restrict__ Wob, float* __restrict__ bcat){
  int bid = blockIdx.x;
  if(bid >= 14336){
    int i = (bid - 14336) * 2048 + threadIdx.x * 8;
    #pragma unroll
    for(int u=0;u<8;++u){
      int j = i + u;
      float v;
      if(j < 2048)      v = bq[j];
      else if(j < 4096) v = bk[j - 2048];
      else if(j < 6144) v = bv[j - 4096];
      else              v = bg[j - 6144];
      bcat[j] = v;
    }
    return;
  }
  const float* s; unsigned short* d; long off;
  if(bid < 4096){ s = x; d = xb; off = (long)bid*2048; }
  else if(bid < 6144){ s = Wq; d = Wcat;            off = (long)(bid-4096)*2048; }
  else if(bid < 8192){ s = Wk; d = Wcat + 4194304L; off = (long)(bid-6144)*2048; }
  else if(bid < 10240){ s = Wv; d = Wcat + 8388608L; off = (long)(bid-8192)*2048; }
  else if(bid < 12288){ s = Wg; d = Wcat + 12582912L; off = (long)(bid-10240)*2048; }
  else { s = Wo; d = Wob; off = (long)(bid-12288)*2048; }
  long i = off + (long)threadIdx.x * 8;
  float4 v0 = *(const float4*)(s + i);
  float4 v1 = *(const float4*)(s + i + 4);
  short8 o;
  o[0]=(short)f2bf(v0.x); o[1]=(short)f2bf(v0.y); o[2]=(short)f2bf(v0.z); o[3]=(short)f2bf(v0.w);
  o[4]=(short)f2bf(v1.x); o[5]=(short)f2bf(v1.y); o[6]=(short)f2bf(v1.z); o[7]=(short)f2bf(v1.w);
  *(short8*)(d + i) = o;
}

// ================= 256x256 GEMM, 8-phase schedule, 32x32x16 MFMA =================
// Same staging/LDS layout/phases as the banked R13 kernel; only the fragment
// reads + MFMA shape change. 32x32x16 delivers 4060 FLOP/cy vs 16x16x32's 3378
// (-17% matrix-pipe time) at identical ds_read traffic.
// A/B frag: row = lane&31, k-chunk = (lane>>5)*8 (natural extension of the
// validated 16x16 mapping). C/D: col=lane&31, row=(reg&3)+8*(reg>>2)+4*(lane>>5).
__global__ __launch_bounds__(512, 2)
void k_gemm256(const unsigned short* __restrict__ A,
               const unsigned short* __restrict__ Bt,
               unsigned short* __restrict__ Y,
               const float* __restrict__ bias)
{
  extern __shared__ unsigned short lds[];
  constexpr int K = 2048;
  constexpr int NKT = K / 64;               // 32

  const int tid = threadIdx.x;
  const int wave = tid >> 6, lane = tid & 63;
  const int wr = wave >> 2, wc = wave & 3;
  const int l31 = lane & 31, l2g = lane >> 5;

  int bid = blockIdx.x;
  int g = bid & 7, w = bid >> 3;
  int bm = (g & 1) * 8 + (w & 7);           // 0..15
  int bn = (g >> 1) * 8 + (w >> 3);         // 0..31

  const unsigned short* Ag = A  + (long)bm * 256 * K;
  const unsigned short* Bg = Bt + (long)bn * 256 * K;

  // staging geometry (unchanged): 8-row gload blocks, pre-swizzled source col
  const int sr = (lane >> 3);
  const int sc = ((lane & 7) ^ sr) * 8;
  // read col swizzle for 32-row frags: chunk = ks*2 + l2g, pos = chunk ^ (row&7);
  // row&7 == lane&7 for all frag rows (offsets are multiples of 8)
  int colz[4];
  #pragma unroll
  for(int ks=0; ks<4; ++ks) colz[ks] = ((ks*2 + l2g) ^ (lane & 7)) << 4;

  floatx16 acc[4][2] = {};    // [mt][nt] 32x32 tiles (wave tile 128x64)
  const char* ldsc = (const char*)lds;
  short8 Aa[8], Ab[8], Ba[4], Bb[4];

#define STG_A(buf, kt, mh) do{                                                        \
    _Pragma("unroll")                                                                 \
    for(int g2=0; g2<2; ++g2){                                                        \
      gload_lds16(Ag + (long)(wr*128 + (mh)*64 + wc*16 + g2*8 + sr)*K                 \
                     + (long)(kt)*64 + sc,                                            \
                  &lds[(buf)*16384 + wr*8192 + ((mh)*64 + wc*16 + g2*8)*64 + lane*8]);\
    }                                                                                 \
  }while(0)

#define STG_B(buf, kt, nh) do{                                                        \
    _Pragma("unroll")                                                                 \
    for(int g2=0; g2<2; ++g2){                                                        \
      gload_lds16(Bg + (long)(wc*64 + (nh)*32 + wr*16 + g2*8 + sr)*K                  \
                     + (long)(kt)*64 + sc,                                            \
                  &lds[32768 + (buf)*16384 + (wc>>1)*8192                             \
                       + ((wc&1)*64 + (nh)*32 + wr*16 + g2*8)*64 + lane*8]);          \
    }                                                                                 \
  }while(0)

// A quadrant-half (mh): 2 subtiles of 32 rows x 4 ksteps -> 8 short8
#define RD_A(dst, buf, mh) do{                                                        \
    const char* _b = ldsc + ((buf)*16384 + wr*8192)*2;                                \
    _Pragma("unroll")                                                                 \
    for(int sub=0; sub<2; ++sub){                                                     \
      const int _rb = ((mh)*64 + sub*32 + l31) << 7;                                  \
      _Pragma("unroll")                                                               \
      for(int ks=0; ks<4; ++ks)                                                       \
        dst[sub*4+ks] = *(const short8*)(_b + _rb + colz[ks]);                        \
    }                                                                                 \
  }while(0)

// B quadrant (nh): 1 subtile of 32 rows x 4 ksteps -> 4 short8
#define RD_B(dst, buf, nh) do{                                                        \
    const char* _b = ldsc + (32768 + (buf)*16384 + (wc>>1)*8192)*2;                   \
    const int _rb = ((wc&1)*64 + (nh)*32 + l31) << 7;                                 \
    _Pragma("unroll")                                                                 \
    for(int ks=0; ks<4; ++ks)                                                         \
      dst[ks] = *(const short8*)(_b + _rb + colz[ks]);                                \
  }while(0)

#define MFQ(mh, nh, As, Bs) do{                                                       \
    __builtin_amdgcn_s_setprio(1);                                                    \
    _Pragma("unroll")                                                                 \
    for(int sub=0; sub<2; ++sub)                                                      \
      _Pragma("unroll")                                                               \
      for(int ks=0; ks<4; ++ks)                                                       \
        acc[(mh)*2+sub][nh] = __builtin_amdgcn_mfma_f32_32x32x16_bf16(                \
            As[sub*4+ks], Bs[ks], acc[(mh)*2+sub][nh], 0,0,0);                        \
    __builtin_amdgcn_s_setprio(0);                                                    \
  }while(0)

#define VM4   asm volatile("s_waitcnt vmcnt(4)" ::: "memory")
#define BAR   __builtin_amdgcn_s_barrier()
#define SCHED __builtin_amdgcn_sched_barrier(0)

  STG_A(0, 0, 0); STG_B(0, 0, 0); STG_B(0, 0, 1); STG_A(0, 0, 1);
  VM4;
  BAR;
  SCHED;

  #pragma unroll 1
  for(int i=0; i<NKT/2; ++i){
    const int t1 = 2*i + 1;
    const int t2 = (2*i + 2) & (NKT - 1);

    RD_A(Aa, 0, 0); RD_B(Ba, 0, 0);
    STG_A(1, t1, 0); STG_B(1, t1, 0);
    VM4; BAR;
    MFQ(0, 0, Aa, Ba);
    BAR; SCHED;
    RD_B(Bb, 0, 1);
    STG_B(1, t1, 1);
    VM4; BAR;
    MFQ(0, 1, Aa, Bb);
    BAR; SCHED;
    RD_A(Ab, 0, 1);
    STG_A(1, t1, 1);
    VM4; BAR;
    MFQ(1, 1, Ab, Bb);
    BAR; SCHED;
    VM4; BAR;
    MFQ(1, 0, Ab, Ba);
    BAR; SCHED;

    RD_A(Aa, 1, 0); RD_B(Ba, 1, 0);
    STG_A(0, t2, 0); STG_B(0, t2, 0);
    VM4; BAR;
    MFQ(0, 0, Aa, Ba);
    BAR; SCHED;
    RD_B(Bb, 1, 1);
    STG_B(0, t2, 1);
    VM4; BAR;
    MFQ(0, 1, Aa, Bb);
    BAR; SCHED;
    RD_A(Ab, 1, 1);
    STG_A(0, t2, 1);
    VM4; BAR;
    MFQ(1, 1, Ab, Bb);
    BAR; SCHED;
    VM4; BAR;
    MFQ(1, 0, Ab, Ba);
    BAR; SCHED;
  }
#undef STG_A
#undef STG_B
#undef RD_A
#undef RD_B
#undef MFQ
#undef VM4
#undef BAR
#undef SCHED

  // ---- epilogue: bias + section transform + decay bake (32x32 C layout) ----
  const int sec = bn >> 3;                  // block-uniform section
  float l2d = 0.f;
  if(sec <= 1){
    const int h = (bn & 7) * 2 + (wc >> 1); // thread-uniform head
    l2d = flog2(1.f - fexp2(-5.f - (float)h));
  }
  #pragma unroll
  for(int mt=0; mt<4; ++mt){
    #pragma unroll
    for(int reg=0; reg<16; ++reg){
      const int rloc = mt*32 + (reg & 3) + 8*(reg >> 2) + 4*l2g;   // 0..127
      const int rowg = bm*256 + wr*128 + rloc;
      float s = 1.f;
      if(sec == 0)      s = fexp2((float)rloc * l2d);              // qd = q * dec^t
      else if(sec == 1) s = KSCALE * fexp2(-(float)rloc * l2d);    // kd
      #pragma unroll
      for(int nt=0; nt<2; ++nt){
        const int col = bn*256 + wc*64 + nt*32 + l31;
        float v = acc[mt][nt][reg] + bias[col];
        if(sec <= 1)      v *= s;
        else if(sec == 3) v = v / (1.f + __expf(-v));              // silu(g)
        Y[(long)rowg * NCAT_ + col] = f2bf(v);
      }
    }
  }
}

// ================= 256x128 GEMM (output projection), 4-phase counted-vmcnt =================
__global__ __launch_bounds__(512, 2)
void k_gemm2(const unsigned short* __restrict__ A,
             const unsigned short* __restrict__ Bt,
             float* __restrict__ outp,
             const float* __restrict__ bias)
{
  extern __shared__ unsigned short lds[];
  constexpr int K = 2048;
  constexpr int NKT = K / 64;               // 32

  const int tid = threadIdx.x;
  const int wave = tid >> 6, lane = tid & 63;
  const int wm = wave >> 1, wn = wave & 1;
  const int l15 = lane & 15;

  int bid = blockIdx.x;
  int g = bid & 7, w = bid >> 3;            // w 0..31
  int bm = (g & 1) * 8 + (w & 7);           // 0..15
  int bn = (g >> 1) * 4 + (w >> 3);         // 0..15

  const unsigned short* Ag = A  + (long)bm * 256 * K;
  const unsigned short* Bg = Bt + (long)bn * 128 * K;

  const int sr = lane >> 3;
  const int sc = ((lane & 7) ^ sr) * 8;
  const int colx[2] = { (((lane>>4)  ) ^ (lane&7)) << 4,
                        (((lane>>4)+4) ^ (lane&7)) << 4 };

  floatx4 acc[4][4] = {};
  const char* ldsc = (const char*)lds;
  short8 Av[8], Bv[4], Bw[4];

#define STG_AB(buf, kt) do{                                                           \
    _Pragma("unroll")                                                                 \
    for(int g2=0; g2<4; ++g2){                                                        \
      gload_lds16(Ag + (long)(wm*64 + wn*32 + g2*8 + sr)*K + (long)(kt)*64 + sc,      \
                  &lds[(buf)*16384 + (wm*64 + wn*32 + g2*8)*64 + lane*8]);            \
    }                                                                                 \
    _Pragma("unroll")                                                                 \
    for(int g2=0; g2<2; ++g2){                                                        \
      gload_lds16(Bg + (long)(wn*64 + wm*16 + g2*8 + sr)*K + (long)(kt)*64 + sc,      \
                  &lds[32768 + (buf)*8192 + (wn*64 + wm*16 + g2*8)*64 + lane*8]);     \
    }                                                                                 \
  }while(0)

#define RD_A2(buf) do{                                                                \
    const char* _b = ldsc + (buf)*32768;                                              \
    _Pragma("unroll")                                                                 \
    for(int ai=0; ai<4; ++ai){                                                        \
      const int _rb = (wm*64 + ai*16 + l15) << 7;                                     \
      Av[ai*2+0] = *(const short8*)(_b + _rb + colx[0]);                              \
      Av[ai*2+1] = *(const short8*)(_b + _rb + colx[1]);                              \
    }                                                                                 \
  }while(0)

#define RD_B2(dst, buf, half) do{                                                     \
    const char* _b = ldsc + 65536 + (buf)*16384;                                      \
    _Pragma("unroll")                                                                 \
    for(int bj=0; bj<2; ++bj){                                                        \
      const int _rb = (wn*64 + ((half)*2+bj)*16 + l15) << 7;                          \
      dst[bj*2+0] = *(const short8*)(_b + _rb + colx[0]);                             \
      dst[bj*2+1] = *(const short8*)(_b + _rb + colx[1]);                             \
    }                                                                                 \
  }while(0)

#define MF8(half, Bs) do{                                                             \
    __builtin_amdgcn_s_setprio(1);                                                    \
    _Pragma("unroll")                                                                 \
    for(int ai=0; ai<4; ++ai)                                                         \
      _Pragma("unroll")                                                               \
      for(int bj=0; bj<2; ++bj)                                                       \
        _Pragma("unroll")                                                             \
        for(int kk=0; kk<2; ++kk)                                                     \
          acc[ai][(half)*2+bj] = __builtin_amdgcn_mfma_f32_16x16x32_bf16(             \
              Av[ai*2+kk], Bs[bj*2+kk], acc[ai][(half)*2+bj], 0,0,0);                 \
    __builtin_amdgcn_s_setprio(0);                                                    \
  }while(0)

#define VM6   asm volatile("s_waitcnt vmcnt(6)" ::: "memory")
#define BAR   __builtin_amdgcn_s_barrier()
#define SCHED __builtin_amdgcn_sched_barrier(0)

  STG_AB(0, 0);   // prologue: tile0 -> buf0 (6 loads in flight)

  #pragma unroll 1
  for(int i=0; i<NKT/2; ++i){
    const int u = 2*i;
    STG_AB(1, u+1);
    VM6; BAR;
    RD_A2(0); RD_B2(Bv, 0, 0);
    MF8(0, Bv);
    SCHED;
    RD_B2(Bw, 0, 1);
    MF8(1, Bw);
    BAR; SCHED;
    STG_AB(0, (u+2) & (NKT-1));
    VM6; BAR;
    RD_A2(1); RD_B2(Bv, 1, 0);
    MF8(0, Bv);
    SCHED;
    RD_B2(Bw, 1, 1);
    MF8(1, Bw);
    BAR; SCHED;
  }
#undef STG_AB
#undef RD_A2
#undef RD_B2
#undef MF8
#undef VM6
#undef BAR
#undef SCHED

  // epilogue: f32 out + bias
  #pragma unroll
  for(int ai=0;ai<4;++ai){
    const int row = bm*256 + wm*64 + ai*16 + ((lane>>4)<<2);
    #pragma unroll
    for(int bj=0;bj<4;++bj){
      const int col = bn*128 + wn*64 + bj*16 + l15;
      const float bs = bias[col];
      #pragma unroll
      for(int r=0;r<4;++r)
        outp[(long)(row + r)*E_ + col] = acc[ai][bj][r] + bs;
    }
  }
}

// ---------------- fused transpose + per-chunk summary (decay pre-baked in Y) ----------------
__global__ __launch_bounds__(256)
void k_chunksumT(const unsigned short* __restrict__ Y,
                 unsigned short* __restrict__ Vt,
                 unsigned short* __restrict__ MS){
  __shared__ unsigned short lt[64][136];    // one op's half-slice [t_loc][d]
  __shared__ unsigned short Kt2[128][72];   // [dk][t_half]
  __shared__ unsigned short Vt2[128][72];   // [dv][t_half]
  int bid = blockIdx.x;                     // 512: bh*16 + c
  int bh = bid >> 4, c = bid & 15, b = bh >> 4, h = bh & 15;
  int tid = threadIdx.x, wave = tid >> 6, lane = tid & 63;
  int wr = wave >> 1, wc = wave & 1;
  float dec = 1.f - fexp2(-5.f - (float)h);

  floatx4 acc[4][4] = {};

  #pragma unroll 1
  for(int h2 = 0; h2 < 2; ++h2){
    // kd half-slice (already decay-baked by GEMM1) -> lt
    #pragma unroll
    for(int p=0;p<4;++p){
      int tl = p*16 + (tid>>4);
      int t  = h2*64 + tl;
      long row = ((long)(b*N_ + c*CH_ + t))*NCAT_ + 2048 + h*128 + (tid&15)*8;
      *(short8*)&lt[tl][(tid&15)*8] = *(const short8*)(Y + row);
    }
    __syncthreads();
    #pragma unroll
    for(int p=0;p<4;++p){
      int dk = p*32 + (tid>>3);
      int tc = (tid&7)*8;
      short8 o;
      #pragma unroll
      for(int u=0;u<8;++u) o[u] = (short)lt[tc+u][dk];
      *(short8*)&Kt2[dk][tc] = o;
    }
    __syncthreads();
    #pragma unroll
    for(int p=0;p<4;++p){
      int tl = p*16 + (tid>>4);
      int t  = h2*64 + tl;
      long row = ((long)(b*N_ + c*CH_ + t))*NCAT_ + 4096 + h*128 + (tid&15)*8;
      *(short8*)&lt[tl][(tid&15)*8] = *(const short8*)(Y + row);
    }
    __syncthreads();
    #pragma unroll
    for(int p=0;p<4;++p){
      int dv = p*32 + (tid>>3);
      int tc = (tid&7)*8;
      short8 o;
      #pragma unroll
      for(int u=0;u<8;++u) o[u] = (short)lt[tc+u][dv];
      *(short8*)&Vt2[dv][tc] = o;
      *(short8*)(Vt + ((long)(bh*128 + dv))*N_ + c*CH_ + h2*64 + tc) = o;
    }
    __syncthreads();
    #pragma unroll
    for(int kk=0;kk<2;++kk){
      int tl = kk*32 + ((lane>>4)<<3);
      short8 af[4], bfr[4];
      #pragma unroll
      for(int i=0;i<4;++i){ int dv = (wr<<6)+(i<<4)+(lane&15); af[i]  = *(const short8*)&Vt2[dv][tl]; }
      #pragma unroll
      for(int j=0;j<4;++j){ int dk = (wc<<6)+(j<<4)+(lane&15); bfr[j] = *(const short8*)&Kt2[dk][tl]; }
      #pragma unroll
      for(int i=0;i<4;++i)
        #pragma unroll
        for(int j=0;j<4;++j)
          acc[i][j] = __builtin_amdgcn_mfma_f32_16x16x32_bf16(af[i], bfr[j], acc[i][j], 0,0,0);
    }
    __syncthreads();
  }

  float scale = fexp2(127.f * flog2(dec));    // dec^{C-1}
  unsigned short* Mo = MS + ((long)bh*NC_ + c) * 16384;
  #pragma unroll
  for(int i=0;i<4;++i)
    #pragma unroll
    for(int j=0;j<4;++j)
      #pragma unroll
      for(int r=0;r<4;++r){
        int dv = (wr<<6)+(i<<4)+((lane>>4)<<2)+r;
        int dk = (wc<<6)+(j<<4)+(lane&15);
        Mo[dv*128 + dk] = f2bf(acc[i][j][r] * scale);
      }
}

// ---------------- parallel scan over chunks (8 elems/thread, 16B accesses) ----------------
__global__ __launch_bounds__(256)
void k_scan(const unsigned short* __restrict__ MS, unsigned short* __restrict__ Scb,
            float* __restrict__ stateOut){
  int bid = blockIdx.x;                 // 256 = bh*8 + p
  int bh = bid >> 3, p = bid & 7;
  int tid = threadIdx.x, h = bh & 15;
  float dec = 1.f - fexp2(-5.f - (float)h);
  float decC = fexp2(128.f * flog2(dec));     // dec^C
  int e0 = p*2048 + tid*8;
  float S[8] = {};
  const unsigned short* base = MS + (long)bh * NC_ * 16384 + e0;
  unsigned short* sb = Scb + (long)bh * NC_ * 16384 + e0;
  for(int c=0;c<NC_;++c){
    short8 m = *(const short8*)(base + (long)c*16384);
    short8 q;
    #pragma unroll
    for(int u=0;u<8;++u){
      q[u] = (short)f2bf(S[u]);
      S[u] = decC * S[u] + bf2f((unsigned short)m[u]);
    }
    *(short8*)(sb + (long)c*16384) = q;
  }
  // final state: element e = dv*128+dk (transposed layout) -> out [b][h][dk][dv]
  int dv = e0 >> 7, dk = e0 & 127;
  float* so = stateOut + (long)bh*16384 + dv;
  #pragma unroll
  for(int u=0;u<8;++u) so[(long)(dk+u)*128] = S[u];
}

// ---------------- retention output: masked QK^T @ V + cross, group-norm, gate ----------------
__global__ __launch_bounds__(256)
void k_ret(const unsigned short* __restrict__ Y, const unsigned short* __restrict__ Vt,
           const unsigned short* __restrict__ Scb, unsigned short* __restrict__ RG){
  __shared__ unsigned short sQ[128*128];   // qd (swizzled)
  __shared__ unsigned short sK[128*128];   // kd ; reused for P
  int bid = blockIdx.x;
  int bh = bid >> 4, c = bid & 15, b = bh >> 4, h = bh & 15;
  int tid = threadIdx.x, w = tid >> 6, lane = tid & 63;
  float dec = 1.f - fexp2(-5.f - (float)h);

  // stage qd,kd via global_load_lds (decay pre-baked): linear dest, pre-swizzled src
  #pragma unroll
  for(int p=0;p<8;++p){
    int t = p*16 + (tid>>4);
    int cs = (lane & 15) ^ (t & 7);
    long src = (long)(b*N_ + c*CH_ + t) * NCAT_ + h*128 + cs*8;
    char* dq = (char*)sQ + p*4096 + (tid>>4)*256 + (lane & 15)*16;
    char* dk = (char*)sK + p*4096 + (tid>>4)*256 + (lane & 15)*16;
    gload_lds16(Y + src,        dq);
    gload_lds16(Y + src + 2048, dk);
  }
  __syncthreads();   // drains vmcnt (gload_lds) + joins

  floatx4 acc[2][8] = {};
  // QK^T (decay dec^{t-s} baked in operands)
  #pragma unroll
  for(int kk=0;kk<4;++kk){
    int cb = (kk<<6) + ((lane>>4)<<4);
    short8 af[2], bfr[8];
    #pragma unroll
    for(int i=0;i<2;++i){ int t = w*32 + (i<<4) + (lane&15); af[i] = *(const short8*)((const char*)sQ + t*256 + (cb ^ ((t&7)<<4))); }
    #pragma unroll
    for(int j=0;j<8;++j){ int s = (j<<4) + (lane&15); bfr[j] = *(const short8*)((const char*)sK + s*256 + (cb ^ ((s&7)<<4))); }
    #pragma unroll
    for(int i=0;i<2;++i)
      #pragma unroll
      for(int j=0;j<8;++j)
        acc[i][j] = __builtin_amdgcn_mfma_f32_16x16x32_bf16(af[i], bfr[j], acc[i][j], 0,0,0);
  }
  __syncthreads();   // all waves done reading sK

  // causal mask, write P (bf16) into sK
  #pragma unroll
  for(int i=0;i<2;++i)
    #pragma unroll
    for(int j=0;j<8;++j)
      #pragma unroll
      for(int r=0;r<4;++r){
        int t = w*32 + (i<<4) + ((lane>>4)<<2) + r;
        int s = (j<<4) + (lane&15);
        float v = (s <= t) ? acc[i][j][r] : 0.f;
        *(unsigned short*)((char*)sK + t*256 + ((s*2) ^ ((t&7)<<4))) = f2bf(v);
      }
  __syncthreads();

  #pragma unroll
  for(int i=0;i<2;++i)
    #pragma unroll
    for(int j=0;j<8;++j)
      #pragma unroll
      for(int u=0;u<4;++u) acc[i][j][u] = 0.f;

  // ret = P @ V
  const unsigned short* Vb = Vt + (long)bh*128*N_ + c*CH_;
  #pragma unroll
  for(int kk=0;kk<4;++kk){
    int cb = (kk<<6) + ((lane>>4)<<4);
    int sg = kk*32 + ((lane>>4)<<3);
    short8 af[2], bfr[8];
    #pragma unroll
    for(int i=0;i<2;++i){ int t = w*32 + (i<<4) + (lane&15); af[i] = *(const short8*)((const char*)sK + t*256 + (cb ^ ((t&7)<<4))); }
    #pragma unroll
    for(int j=0;j<8;++j){ int dv = (j<<4) + (lane&15); bfr[j] = *(const short8*)(Vb + (long)dv*N_ + sg); }
    #pragma unroll
    for(int i=0;i<2;++i)
      #pragma unroll
      for(int j=0;j<8;++j)
        acc[i][j] = __builtin_amdgcn_mfma_f32_16x16x32_bf16(af[i], bfr[j], acc[i][j], 0,0,0);
  }
  // + dec^{t+1} * q @ S_c   (A = qd*dec, B = Scb[dv][dk])
  const unsigned short* Sb = Scb + ((long)bh*NC_ + c) * 16384;
  #pragma unroll
  for(int kk=0;kk<4;++kk){
    int cb = (kk<<6) + ((lane>>4)<<4);
    int kg = kk*32 + ((lane>>4)<<3);
    short8 af[2], bfr[8];
    #pragma unroll
    for(int i=0;i<2;++i){
      int t = w*32 + (i<<4) + (lane&15);
      short8 qv = *(const short8*)((const char*)sQ + t*256 + (cb ^ ((t&7)<<4)));
      #pragma unroll
      for(int u=0;u<8;++u) af[i][u] = (short)f2bf(bf2f((unsigned short)qv[u]) * dec);
    }
    #pragma unroll
    for(int j=0;j<8;++j){ int dv = (j<<4) + (lane&15); bfr[j] = *(const short8*)(Sb + (long)dv*128 + kg); }
    #pragma unroll
    for(int i=0;i<2;++i)
      #pragma unroll
      for(int j=0;j<8;++j)
        acc[i][j] = __builtin_amdgcn_mfma_f32_16x16x32_bf16(af[i], bfr[j], acc[i][j], 0,0,0);
  }

  // group-norm over DV per row, gate, write bf16
  #pragma unroll
  for(int i=0;i<2;++i){
    #pragma unroll
    for(int r=0;r<4;++r){
      float s1 = 0.f, s2 = 0.f;
      #pragma unroll
      for(int j=0;j<8;++j){ float v = acc[i][j][r]; s1 += v; s2 += v*v; }
      #pragma unroll
      for(int off=1; off<16; off<<=1){ s1 += __shfl_xor(s1, off); s2 += __shfl_xor(s2, off); }
      float mu  = s1 * (1.f/128.f);
      float var = s2 * (1.f/128.f) - mu*mu;
      float inv = rsqrtf(var + 1e-6f);
      int t = w*32 + (i<<4) + ((lane>>4)<<2) + r;
      long mrow = (long)(b*N_ + c*CH_ + t);
      #pragma unroll
      for(int j=0;j<8;++j){
        int dv = (j<<4) + (lane&15);
        float v = (acc[i][j][r] - mu) * inv;
        float g = bf2f(Y[mrow*NCAT_ + 6144 + h*128 + dv]);
        RG[mrow*E_ + h*128 + dv] = f2bf(v * g);
      }
    }
  }
}

// ---------------- launch ----------------
extern "C" void kernel_launch(void* const* d_in, const int* in_sizes, int n_in,
                              void* d_out, int out_size, void* d_ws, size_t ws_size,
                              hipStream_t stream) {
  const float* x  = (const float*)d_in[0];
  const float* Wq = (const float*)d_in[1];
  const float* bq = (const float*)d_in[2];
  const float* Wk = (const float*)d_in[3];
  const float* bk = (const float*)d_in[4];
  const float* Wv = (const float*)d_in[5];
  const float* bv = (const float*)d_in[6];
  const float* Wg = (const float*)d_in[7];
  const float* bg = (const float*)d_in[8];
  const float* Wo = (const float*)d_in[9];
  const float* bo = (const float*)d_in[10];

  char* ws = (char*)d_ws;
  unsigned short* xb   = (unsigned short*)(ws + OFF_XB);
  unsigned short* Wcat = (unsigned short*)(ws + OFF_WCAT);
  unsigned short* Wob  = (unsigned short*)(ws + OFF_WOB);
  float*          bcat = (float*)(ws + OFF_BCAT);
  unsigned short* Y    = (unsigned short*)(ws + OFF_Y);
  unsigned short* Vt   = (unsigned short*)(ws + OFF_VT);
  unsigned short* Scb  = (unsigned short*)(ws + OFF_SCB);
  unsigned short* MS   = (unsigned short*)(ws + OFF_WCAT); // bf16, reuse after GEMM1
  unsigned short* RG   = (unsigned short*)(ws + OFF_XB);   // reuse after GEMM1

  float* outp     = (float*)d_out;
  float* stateOut = outp + (long)M_ * E_;   // 8,388,608

  (void)hipFuncSetAttribute((const void*)k_gemm256,
                            hipFuncAttributeMaxDynamicSharedMemorySize, 131072);
  (void)hipFuncSetAttribute((const void*)k_gemm2,
                            hipFuncAttributeMaxDynamicSharedMemorySize, 98304);

  // fused prep (all casts + bias concat)
  k_castall<<<14340, 256, 0, stream>>>(x, Wq, Wk, Wv, Wg, Wo, bq, bk, bv, bg,
                                       xb, Wcat, Wob, bcat);

  // fused QKVG projection (256^2, 8-phase, 32x32x16 MFMA)
  k_gemm256<<<512, 512, 131072, stream>>>(xb, Wcat, Y, bcat);

  // fused transpose + per-chunk summary (writes Vt + MS bf16)
  k_chunksumT<<<512, 256, 0, stream>>>(Y, Vt, MS);

  // sequential-over-chunks scan (parallel over state elements)
  k_scan<<<256, 256, 0, stream>>>(MS, Scb, stateOut);

  // retention output (masked QK^T @ V + cross term, group-norm, gate)
  k_ret<<<512, 256, 0, stream>>>(Y, Vt, Scb, RG);

  // output projection (256x128 4-phase)
  k_gemm2<<<256, 512, 98304, stream>>>(RG, Wob, outp, bo);
}

// Round 15
// 250.691 us; speedup vs baseline: 1.0903x; 1.0903x over previous
//
#include <hip/hip_runtime.h>
#include <hip/hip_bf16.h>

typedef __attribute__((ext_vector_type(8))) short short8;
typedef __attribute__((ext_vector_type(4))) short short4v;
typedef __attribute__((ext_vector_type(4))) float floatx4;

#define DI __device__ __forceinline__

// Problem constants
constexpr int B_ = 2, N_ = 2048, H_ = 16, DK_ = 128, DV_ = 128, E_ = 2048;
constexpr int M_ = B_ * N_;          // 4096 token rows
constexpr int NCAT_ = 4 * E_;        // 8192 = q|k|v|g concat
constexpr int CH_ = 128;             // chunk length
constexpr int NC_ = N_ / CH_;        // 16 chunks
constexpr float KSCALE = 0.08838834764831845f; // 1/sqrt(128)

// Workspace layout (bytes)
constexpr long OFF_XB   = 0;                    // 16MB  bf16 x      (reused as RG after GEMM1)
constexpr long OFF_WCAT = 16777216;             // 32MB  bf16 Wq|Wk|Wv|Wg  (reused as MS bf16 after GEMM1)
constexpr long OFF_WOB  = 50331648;             // 8MB   bf16 Wo
constexpr long OFF_BCAT = 58720256;             // 32KB  f32 concat bias
constexpr long OFF_Y    = 58753024;             // 64MB  bf16 [4096][8192] qd|kd|v|silu(g)
constexpr long OFF_VT   = 142639104;            // 16MB  bf16 Vt  [b][h][dv][t]
constexpr long OFF_SCB  = 159416320;            // 16MB  bf16 per-chunk start states [bh][c][dv][dk]

DI unsigned short f2bf(float f){
  unsigned u = __float_as_uint(f);
  u += 0x7fffu + ((u >> 16) & 1u);
  return (unsigned short)(u >> 16);
}
DI float bf2f(unsigned short s){ return __uint_as_float(((unsigned)s) << 16); }

DI float fexp2(float x){ return __builtin_amdgcn_exp2f(x); }   // v_exp_f32: 2^x
DI float flog2(float x){ return __builtin_amdgcn_logf(x); }    // v_log_f32: log2(x)

DI void gload_lds16(const void* g, void* l){
  __builtin_amdgcn_global_load_lds(
      (const __attribute__((address_space(1))) unsigned int*)g,
      (__attribute__((address_space(3))) unsigned int*)l, 16, 0, 0);
}

// ---------------- fused prep: all f32->bf16 casts + bias concat ----------------
__global__ void k_castall(const float* __restrict__ x,
                          const float* __restrict__ Wq, const float* __restrict__ Wk,
                          const float* __restrict__ Wv, const float* __restrict__ Wg,
                          const float* __restrict__ Wo,
                          const float* __restrict__ bq, const float* __restrict__ bk,
                          const float* __restrict__ bv, const float* __restrict__ bg,
                          unsigned short* __restrict__ xb, unsigned short* __restrict__ Wcat,
                          unsigned short* __restrict__ Wob, float* __restrict__ bcat){
  int bid = blockIdx.x;
  if(bid >= 14336){
    int i = (bid - 14336) * 2048 + threadIdx.x * 8;
    #pragma unroll
    for(int u=0;u<8;++u){
      int j = i + u;
      float v;
      if(j < 2048)      v = bq[j];
      else if(j < 4096) v = bk[j - 2048];
      else if(j < 6144) v = bv[j - 4096];
      else              v = bg[j - 6144];
      bcat[j] = v;
    }
    return;
  }
  const float* s; unsigned short* d; long off;
  if(bid < 4096){ s = x; d = xb; off = (long)bid*2048; }
  else if(bid < 6144){ s = Wq; d = Wcat;            off = (long)(bid-4096)*2048; }
  else if(bid < 8192){ s = Wk; d = Wcat + 4194304L; off = (long)(bid-6144)*2048; }
  else if(bid < 10240){ s = Wv; d = Wcat + 8388608L; off = (long)(bid-8192)*2048; }
  else if(bid < 12288){ s = Wg; d = Wcat + 12582912L; off = (long)(bid-10240)*2048; }
  else { s = Wo; d = Wob; off = (long)(bid-12288)*2048; }
  long i = off + (long)threadIdx.x * 8;
  float4 v0 = *(const float4*)(s + i);
  float4 v1 = *(const float4*)(s + i + 4);
  short8 o;
  o[0]=(short)f2bf(v0.x); o[1]=(short)f2bf(v0.y); o[2]=(short)f2bf(v0.z); o[3]=(short)f2bf(v0.w);
  o[4]=(short)f2bf(v1.x); o[5]=(short)f2bf(v1.y); o[6]=(short)f2bf(v1.z); o[7]=(short)f2bf(v1.w);
  *(short8*)(d + i) = o;
}

// ================= 256x256 GEMM, 8-phase schedule (banked, 16x16x32 MFMA) =================
// Epilogue bakes retention decay into q/k sections with cheap v_exp/v_log math.
__global__ __launch_bounds__(512, 2)
void k_gemm256(const unsigned short* __restrict__ A,
               const unsigned short* __restrict__ Bt,
               unsigned short* __restrict__ Y,
               const float* __restrict__ bias)
{
  extern __shared__ unsigned short lds[];
  constexpr int K = 2048;
  constexpr int NKT = K / 64;               // 32

  const int tid = threadIdx.x;
  const int wave = tid >> 6, lane = tid & 63;
  const int wr = wave >> 2, wc = wave & 3;
  const int l15 = lane & 15;

  int bid = blockIdx.x;
  int g = bid & 7, w = bid >> 3;
  int bm = (g & 1) * 8 + (w & 7);           // 0..15
  int bn = (g >> 1) * 8 + (w >> 3);         // 0..31

  const unsigned short* Ag = A  + (long)bm * 256 * K;
  const unsigned short* Bg = Bt + (long)bn * 256 * K;

  const int sr = (lane >> 3);
  const int sc = ((lane & 7) ^ sr) * 8;
  const int colx[2] = { ((0 + (lane>>4)) ^ (lane&7)) << 4,
                        ((4 + (lane>>4)) ^ (lane&7)) << 4 };

  floatx4 acc[8][4] = {};     // [mh*4+ai][nh*2+bj]
  const char* ldsc = (const char*)lds;
  short8 Aa[8], Ab[8], Ba[4], Bb[4];

#define STG_A(buf, kt, mh) do{                                                        \
    _Pragma("unroll")                                                                 \
    for(int g2=0; g2<2; ++g2){                                                        \
      gload_lds16(Ag + (long)(wr*128 + (mh)*64 + wc*16 + g2*8 + sr)*K                 \
                     + (long)(kt)*64 + sc,                                            \
                  &lds[(buf)*16384 + wr*8192 + ((mh)*64 + wc*16 + g2*8)*64 + lane*8]);\
    }                                                                                 \
  }while(0)

#define STG_B(buf, kt, nh) do{                                                        \
    _Pragma("unroll")                                                                 \
    for(int g2=0; g2<2; ++g2){                                                        \
      gload_lds16(Bg + (long)(wc*64 + (nh)*32 + wr*16 + g2*8 + sr)*K                  \
                     + (long)(kt)*64 + sc,                                            \
                  &lds[32768 + (buf)*16384 + (wc>>1)*8192                             \
                       + ((wc&1)*64 + (nh)*32 + wr*16 + g2*8)*64 + lane*8]);          \
    }                                                                                 \
  }while(0)

#define RD_A(dst, buf, mh) do{                                                        \
    const char* _b = ldsc + ((buf)*16384 + wr*8192)*2;                                \
    _Pragma("unroll")                                                                 \
    for(int ai=0; ai<4; ++ai){                                                        \
      const int _rb = ((mh)*64 + ai*16 + l15) << 7;                                   \
      dst[ai*2+0] = *(const short8*)(_b + _rb + colx[0]);                             \
      dst[ai*2+1] = *(const short8*)(_b + _rb + colx[1]);                             \
    }                                                                                 \
  }while(0)

#define RD_B(dst, buf, nh) do{                                                        \
    const char* _b = ldsc + (32768 + (buf)*16384 + (wc>>1)*8192)*2;                   \
    _Pragma("unroll")                                                                 \
    for(int bj=0; bj<2; ++bj){                                                        \
      const int _rb = ((wc&1)*64 + (nh)*32 + bj*16 + l15) << 7;                       \
      dst[bj*2+0] = *(const short8*)(_b + _rb + colx[0]);                             \
      dst[bj*2+1] = *(const short8*)(_b + _rb + colx[1]);                             \
    }                                                                                 \
  }while(0)

#define MFQ(mh, nh, As, Bs) do{                                                       \
    __builtin_amdgcn_s_setprio(1);                                                    \
    _Pragma("unroll")                                                                 \
    for(int ai=0; ai<4; ++ai)                                                         \
      _Pragma("unroll")                                                               \
      for(int bj=0; bj<2; ++bj)                                                       \
        _Pragma("unroll")                                                             \
        for(int kk=0; kk<2; ++kk)                                                     \
          acc[(mh)*4+ai][(nh)*2+bj] = __builtin_amdgcn_mfma_f32_16x16x32_bf16(        \
              As[ai*2+kk], Bs[bj*2+kk], acc[(mh)*4+ai][(nh)*2+bj], 0,0,0);            \
    __builtin_amdgcn_s_setprio(0);                                                    \
  }while(0)

#define VM4   asm volatile("s_waitcnt vmcnt(4)" ::: "memory")
#define BAR   __builtin_amdgcn_s_barrier()
#define SCHED __builtin_amdgcn_sched_barrier(0)

  STG_A(0, 0, 0); STG_B(0, 0, 0); STG_B(0, 0, 1); STG_A(0, 0, 1);
  VM4;
  BAR;
  SCHED;

  #pragma unroll 1
  for(int i=0; i<NKT/2; ++i){
    const int t1 = 2*i + 1;
    const int t2 = (2*i + 2) & (NKT - 1);

    RD_A(Aa, 0, 0); RD_B(Ba, 0, 0);
    STG_A(1, t1, 0); STG_B(1, t1, 0);
    VM4; BAR;
    MFQ(0, 0, Aa, Ba);
    BAR; SCHED;
    RD_B(Bb, 0, 1);
    STG_B(1, t1, 1);
    VM4; BAR;
    MFQ(0, 1, Aa, Bb);
    BAR; SCHED;
    RD_A(Ab, 0, 1);
    STG_A(1, t1, 1);
    VM4; BAR;
    MFQ(1, 1, Ab, Bb);
    BAR; SCHED;
    VM4; BAR;
    MFQ(1, 0, Ab, Ba);
    BAR; SCHED;

    RD_A(Aa, 1, 0); RD_B(Ba, 1, 0);
    STG_A(0, t2, 0); STG_B(0, t2, 0);
    VM4; BAR;
    MFQ(0, 0, Aa, Ba);
    BAR; SCHED;
    RD_B(Bb, 1, 1);
    STG_B(0, t2, 1);
    VM4; BAR;
    MFQ(0, 1, Aa, Bb);
    BAR; SCHED;
    RD_A(Ab, 1, 1);
    STG_A(0, t2, 1);
    VM4; BAR;
    MFQ(1, 1, Ab, Bb);
    BAR; SCHED;
    VM4; BAR;
    MFQ(1, 0, Ab, Ba);
    BAR; SCHED;
  }
#undef STG_A
#undef STG_B
#undef RD_A
#undef RD_B
#undef MFQ
#undef VM4
#undef BAR
#undef SCHED

  // ---- epilogue: bias + section transform + decay bake (cheap) ----
  const int sec = bn >> 3;                  // block-uniform section
  float scl[32];                            // [mh*16 + ai*4 + r], statically indexed
  if(sec <= 1){
    const int h = (bn & 7) * 2 + (wc >> 1); // thread-uniform head
    const float l2d = flog2(1.f - fexp2(-5.f - (float)h));
    #pragma unroll
    for(int mh=0;mh<2;++mh)
      #pragma unroll
      for(int ai=0;ai<4;++ai)
        #pragma unroll
        for(int r=0;r<4;++r){
          const float e = (float)(mh*64 + ai*16 + ((lane>>4)<<2) + r);
          scl[mh*16+ai*4+r] = (sec == 0) ? fexp2(e * l2d)
                                         : KSCALE * fexp2(-e * l2d);
        }
  }
  #pragma unroll
  for(int mh=0;mh<2;++mh){
    #pragma unroll
    for(int ai=0;ai<4;++ai){
      const int rowi = bm*256 + wr*128 + mh*64 + ai*16 + ((lane>>4)<<2);
      #pragma unroll
      for(int nh=0;nh<2;++nh){
        #pragma unroll
        for(int bj=0;bj<2;++bj){
          const int col = bn*256 + wc*64 + nh*32 + bj*16 + l15;
          const float bs = bias[col];
          #pragma unroll
          for(int r=0;r<4;++r){
            float v = acc[mh*4+ai][nh*2+bj][r] + bs;
            if(sec <= 1)      v *= scl[mh*16+ai*4+r];        // qd / kd bake
            else if(sec == 3) v = v / (1.f + __expf(-v));    // silu(g)
            Y[(long)(rowi + r) * NCAT_ + col] = f2bf(v);
          }
        }
      }
    }
  }
}

// ================= 256x128 GEMM (output projection), 4-phase counted-vmcnt =================
__global__ __launch_bounds__(512, 2)
void k_gemm2(const unsigned short* __restrict__ A,
             const unsigned short* __restrict__ Bt,
             float* __restrict__ outp,
             const float* __restrict__ bias)
{
  extern __shared__ unsigned short lds[];
  constexpr int K = 2048;
  constexpr int NKT = K / 64;               // 32

  const int tid = threadIdx.x;
  const int wave = tid >> 6, lane = tid & 63;
  const int wm = wave >> 1, wn = wave & 1;
  const int l15 = lane & 15;

  int bid = blockIdx.x;
  int g = bid & 7, w = bid >> 3;            // w 0..31
  int bm = (g & 1) * 8 + (w & 7);           // 0..15
  int bn = (g >> 1) * 4 + (w >> 3);         // 0..15

  const unsigned short* Ag = A  + (long)bm * 256 * K;
  const unsigned short* Bg = Bt + (long)bn * 128 * K;

  const int sr = lane >> 3;
  const int sc = ((lane & 7) ^ sr) * 8;
  const int colx[2] = { (((lane>>4)  ) ^ (lane&7)) << 4,
                        (((lane>>4)+4) ^ (lane&7)) << 4 };

  floatx4 acc[4][4] = {};
  const char* ldsc = (const char*)lds;
  short8 Av[8], Bv[4], Bw[4];

#define STG_AB(buf, kt) do{                                                           \
    _Pragma("unroll")                                                                 \
    for(int g2=0; g2<4; ++g2){                                                        \
      gload_lds16(Ag + (long)(wm*64 + wn*32 + g2*8 + sr)*K + (long)(kt)*64 + sc,      \
                  &lds[(buf)*16384 + (wm*64 + wn*32 + g2*8)*64 + lane*8]);            \
    }                                                                                 \
    _Pragma("unroll")                                                                 \
    for(int g2=0; g2<2; ++g2){                                                        \
      gload_lds16(Bg + (long)(wn*64 + wm*16 + g2*8 + sr)*K + (long)(kt)*64 + sc,      \
                  &lds[32768 + (buf)*8192 + (wn*64 + wm*16 + g2*8)*64 + lane*8]);     \
    }                                                                                 \
  }while(0)

#define RD_A2(buf) do{                                                                \
    const char* _b = ldsc + (buf)*32768;                                              \
    _Pragma("unroll")                                                                 \
    for(int ai=0; ai<4; ++ai){                                                        \
      const int _rb = (wm*64 + ai*16 + l15) << 7;                                     \
      Av[ai*2+0] = *(const short8*)(_b + _rb + colx[0]);                              \
      Av[ai*2+1] = *(const short8*)(_b + _rb + colx[1]);                              \
    }                                                                                 \
  }while(0)

#define RD_B2(dst, buf, half) do{                                                     \
    const char* _b = ldsc + 65536 + (buf)*16384;                                      \
    _Pragma("unroll")                                                                 \
    for(int bj=0; bj<2; ++bj){                                                        \
      const int _rb = (wn*64 + ((half)*2+bj)*16 + l15) << 7;                          \
      dst[bj*2+0] = *(const short8*)(_b + _rb + colx[0]);                             \
      dst[bj*2+1] = *(const short8*)(_b + _rb + colx[1]);                             \
    }                                                                                 \
  }while(0)

#define MF8(half, Bs) do{                                                             \
    __builtin_amdgcn_s_setprio(1);                                                    \
    _Pragma("unroll")                                                                 \
    for(int ai=0; ai<4; ++ai)                                                         \
      _Pragma("unroll")                                                               \
      for(int bj=0; bj<2; ++bj)                                                       \
        _Pragma("unroll")                                                             \
        for(int kk=0; kk<2; ++kk)                                                     \
          acc[ai][(half)*2+bj] = __builtin_amdgcn_mfma_f32_16x16x32_bf16(             \
              Av[ai*2+kk], Bs[bj*2+kk], acc[ai][(half)*2+bj], 0,0,0);                 \
    __builtin_amdgcn_s_setprio(0);                                                    \
  }while(0)

#define VM6   asm volatile("s_waitcnt vmcnt(6)" ::: "memory")
#define BAR   __builtin_amdgcn_s_barrier()
#define SCHED __builtin_amdgcn_sched_barrier(0)

  STG_AB(0, 0);   // prologue: tile0 -> buf0 (6 loads in flight)

  #pragma unroll 1
  for(int i=0; i<NKT/2; ++i){
    const int u = 2*i;
    STG_AB(1, u+1);
    VM6; BAR;
    RD_A2(0); RD_B2(Bv, 0, 0);
    MF8(0, Bv);
    SCHED;
    RD_B2(Bw, 0, 1);
    MF8(1, Bw);
    BAR; SCHED;
    STG_AB(0, (u+2) & (NKT-1));
    VM6; BAR;
    RD_A2(1); RD_B2(Bv, 1, 0);
    MF8(0, Bv);
    SCHED;
    RD_B2(Bw, 1, 1);
    MF8(1, Bw);
    BAR; SCHED;
  }
#undef STG_AB
#undef RD_A2
#undef RD_B2
#undef MF8
#undef VM6
#undef BAR
#undef SCHED

  // epilogue: f32 out + bias
  #pragma unroll
  for(int ai=0;ai<4;++ai){
    const int row = bm*256 + wm*64 + ai*16 + ((lane>>4)<<2);
    #pragma unroll
    for(int bj=0;bj<4;++bj){
      const int col = bn*128 + wn*64 + bj*16 + l15;
      const float bs = bias[col];
      #pragma unroll
      for(int r=0;r<4;++r)
        outp[(long)(row + r)*E_ + col] = acc[ai][bj][r] + bs;
    }
  }
}

// ---------------- fused transpose + per-chunk summary (decay pre-baked in Y) ----------------
__global__ __launch_bounds__(256)
void k_chunksumT(const unsigned short* __restrict__ Y,
                 unsigned short* __restrict__ Vt,
                 unsigned short* __restrict__ MS){
  __shared__ unsigned short lt[64][136];    // one op's half-slice [t_loc][d]
  __shared__ unsigned short Kt2[128][72];   // [dk][t_half]
  __shared__ unsigned short Vt2[128][72];   // [dv][t_half]
  int bid = blockIdx.x;                     // 512: bh*16 + c
  int bh = bid >> 4, c = bid & 15, b = bh >> 4, h = bh & 15;
  int tid = threadIdx.x, wave = tid >> 6, lane = tid & 63;
  int wr = wave >> 1, wc = wave & 1;
  float dec = 1.f - fexp2(-5.f - (float)h);

  floatx4 acc[4][4] = {};

  #pragma unroll 1
  for(int h2 = 0; h2 < 2; ++h2){
    // kd half-slice (already decay-baked by GEMM1) -> lt
    #pragma unroll
    for(int p=0;p<4;++p){
      int tl = p*16 + (tid>>4);
      int t  = h2*64 + tl;
      long row = ((long)(b*N_ + c*CH_ + t))*NCAT_ + 2048 + h*128 + (tid&15)*8;
      *(short8*)&lt[tl][(tid&15)*8] = *(const short8*)(Y + row);
    }
    __syncthreads();
    #pragma unroll
    for(int p=0;p<4;++p){
      int dk = p*32 + (tid>>3);
      int tc = (tid&7)*8;
      short8 o;
      #pragma unroll
      for(int u=0;u<8;++u) o[u] = (short)lt[tc+u][dk];
      *(short8*)&Kt2[dk][tc] = o;
    }
    __syncthreads();
    #pragma unroll
    for(int p=0;p<4;++p){
      int tl = p*16 + (tid>>4);
      int t  = h2*64 + tl;
      long row = ((long)(b*N_ + c*CH_ + t))*NCAT_ + 4096 + h*128 + (tid&15)*8;
      *(short8*)&lt[tl][(tid&15)*8] = *(const short8*)(Y + row);
    }
    __syncthreads();
    #pragma unroll
    for(int p=0;p<4;++p){
      int dv = p*32 + (tid>>3);
      int tc = (tid&7)*8;
      short8 o;
      #pragma unroll
      for(int u=0;u<8;++u) o[u] = (short)lt[tc+u][dv];
      *(short8*)&Vt2[dv][tc] = o;
      *(short8*)(Vt + ((long)(bh*128 + dv))*N_ + c*CH_ + h2*64 + tc) = o;
    }
    __syncthreads();
    #pragma unroll
    for(int kk=0;kk<2;++kk){
      int tl = kk*32 + ((lane>>4)<<3);
      short8 af[4], bfr[4];
      #pragma unroll
      for(int i=0;i<4;++i){ int dv = (wr<<6)+(i<<4)+(lane&15); af[i]  = *(const short8*)&Vt2[dv][tl]; }
      #pragma unroll
      for(int j=0;j<4;++j){ int dk = (wc<<6)+(j<<4)+(lane&15); bfr[j] = *(const short8*)&Kt2[dk][tl]; }
      #pragma unroll
      for(int i=0;i<4;++i)
        #pragma unroll
        for(int j=0;j<4;++j)
          acc[i][j] = __builtin_amdgcn_mfma_f32_16x16x32_bf16(af[i], bfr[j], acc[i][j], 0,0,0);
    }
    __syncthreads();
  }

  float scale = fexp2(127.f * flog2(dec));    // dec^{C-1}
  unsigned short* Mo = MS + ((long)bh*NC_ + c) * 16384;
  #pragma unroll
  for(int i=0;i<4;++i)
    #pragma unroll
    for(int j=0;j<4;++j)
      #pragma unroll
      for(int r=0;r<4;++r){
        int dv = (wr<<6)+(i<<4)+((lane>>4)<<2)+r;
        int dk = (wc<<6)+(j<<4)+(lane&15);
        Mo[dv*128 + dk] = f2bf(acc[i][j][r] * scale);
      }
}

// ---------------- parallel scan over chunks (8 elems/thread, 16B accesses) ----------------
__global__ __launch_bounds__(256)
void k_scan(const unsigned short* __restrict__ MS, unsigned short* __restrict__ Scb,
            float* __restrict__ stateOut){
  int bid = blockIdx.x;                 // 256 = bh*8 + p
  int bh = bid >> 3, p = bid & 7;
  int tid = threadIdx.x, h = bh & 15;
  float dec = 1.f - fexp2(-5.f - (float)h);
  float decC = fexp2(128.f * flog2(dec));     // dec^C
  int e0 = p*2048 + tid*8;
  float S[8] = {};
  const unsigned short* base = MS + (long)bh * NC_ * 16384 + e0;
  unsigned short* sb = Scb + (long)bh * NC_ * 16384 + e0;
  for(int c=0;c<NC_;++c){
    short8 m = *(const short8*)(base + (long)c*16384);
    short8 q;
    #pragma unroll
    for(int u=0;u<8;++u){
      q[u] = (short)f2bf(S[u]);
      S[u] = decC * S[u] + bf2f((unsigned short)m[u]);
    }
    *(short8*)(sb + (long)c*16384) = q;
  }
  // final state: element e = dv*128+dk (transposed layout) -> out [b][h][dk][dv]
  int dv = e0 >> 7, dk = e0 & 127;
  float* so = stateOut + (long)bh*16384 + dv;
  #pragma unroll
  for(int u=0;u<8;++u) so[(long)(dk+u)*128] = S[u];
}

// ---------------- retention output: masked QK^T @ V + cross, group-norm, gate ----------------
__global__ __launch_bounds__(256)
void k_ret(const unsigned short* __restrict__ Y, const unsigned short* __restrict__ Vt,
           const unsigned short* __restrict__ Scb, unsigned short* __restrict__ RG){
  __shared__ unsigned short sQ[128*128];   // qd (swizzled)
  __shared__ unsigned short sK[128*128];   // kd ; reused for P
  int bid = blockIdx.x;
  int bh = bid >> 4, c = bid & 15, b = bh >> 4, h = bh & 15;
  int tid = threadIdx.x, w = tid >> 6, lane = tid & 63;
  float dec = 1.f - fexp2(-5.f - (float)h);

  // stage qd,kd via global_load_lds (decay pre-baked): linear dest, pre-swizzled src
  #pragma unroll
  for(int p=0;p<8;++p){
    int t = p*16 + (tid>>4);
    int cs = (lane & 15) ^ (t & 7);
    long src = (long)(b*N_ + c*CH_ + t) * NCAT_ + h*128 + cs*8;
    char* dq = (char*)sQ + p*4096 + (tid>>4)*256 + (lane & 15)*16;
    char* dk = (char*)sK + p*4096 + (tid>>4)*256 + (lane & 15)*16;
    gload_lds16(Y + src,        dq);
    gload_lds16(Y + src + 2048, dk);
  }
  __syncthreads();   // drains vmcnt (gload_lds) + joins

  floatx4 acc[2][8] = {};
  // QK^T (decay dec^{t-s} baked in operands)
  #pragma unroll
  for(int kk=0;kk<4;++kk){
    int cb = (kk<<6) + ((lane>>4)<<4);
    short8 af[2], bfr[8];
    #pragma unroll
    for(int i=0;i<2;++i){ int t = w*32 + (i<<4) + (lane&15); af[i] = *(const short8*)((const char*)sQ + t*256 + (cb ^ ((t&7)<<4))); }
    #pragma unroll
    for(int j=0;j<8;++j){ int s = (j<<4) + (lane&15); bfr[j] = *(const short8*)((const char*)sK + s*256 + (cb ^ ((s&7)<<4))); }
    #pragma unroll
    for(int i=0;i<2;++i)
      #pragma unroll
      for(int j=0;j<8;++j)
        acc[i][j] = __builtin_amdgcn_mfma_f32_16x16x32_bf16(af[i], bfr[j], acc[i][j], 0,0,0);
  }
  __syncthreads();   // all waves done reading sK

  // causal mask, write P (bf16) into sK
  #pragma unroll
  for(int i=0;i<2;++i)
    #pragma unroll
    for(int j=0;j<8;++j)
      #pragma unroll
      for(int r=0;r<4;++r){
        int t = w*32 + (i<<4) + ((lane>>4)<<2) + r;
        int s = (j<<4) + (lane&15);
        float v = (s <= t) ? acc[i][j][r] : 0.f;
        *(unsigned short*)((char*)sK + t*256 + ((s*2) ^ ((t&7)<<4))) = f2bf(v);
      }
  __syncthreads();

  #pragma unroll
  for(int i=0;i<2;++i)
    #pragma unroll
    for(int j=0;j<8;++j)
      #pragma unroll
      for(int u=0;u<4;++u) acc[i][j][u] = 0.f;

  // ret = P @ V
  const unsigned short* Vb = Vt + (long)bh*128*N_ + c*CH_;
  #pragma unroll
  for(int kk=0;kk<4;++kk){
    int cb = (kk<<6) + ((lane>>4)<<4);
    int sg = kk*32 + ((lane>>4)<<3);
    short8 af[2], bfr[8];
    #pragma unroll
    for(int i=0;i<2;++i){ int t = w*32 + (i<<4) + (lane&15); af[i] = *(const short8*)((const char*)sK + t*256 + (cb ^ ((t&7)<<4))); }
    #pragma unroll
    for(int j=0;j<8;++j){ int dv = (j<<4) + (lane&15); bfr[j] = *(const short8*)(Vb + (long)dv*N_ + sg); }
    #pragma unroll
    for(int i=0;i<2;++i)
      #pragma unroll
      for(int j=0;j<8;++j)
        acc[i][j] = __builtin_amdgcn_mfma_f32_16x16x32_bf16(af[i], bfr[j], acc[i][j], 0,0,0);
  }
  // + dec^{t+1} * q @ S_c   (A = qd*dec, B = Scb[dv][dk])
  const unsigned short* Sb = Scb + ((long)bh*NC_ + c) * 16384;
  #pragma unroll
  for(int kk=0;kk<4;++kk){
    int cb = (kk<<6) + ((lane>>4)<<4);
    int kg = kk*32 + ((lane>>4)<<3);
    short8 af[2], bfr[8];
    #pragma unroll
    for(int i=0;i<2;++i){
      int t = w*32 + (i<<4) + (lane&15);
      short8 qv = *(const short8*)((const char*)sQ + t*256 + (cb ^ ((t&7)<<4)));
      #pragma unroll
      for(int u=0;u<8;++u) af[i][u] = (short)f2bf(bf2f((unsigned short)qv[u]) * dec);
    }
    #pragma unroll
    for(int j=0;j<8;++j){ int dv = (j<<4) + (lane&15); bfr[j] = *(const short8*)(Sb + (long)dv*128 + kg); }
    #pragma unroll
    for(int i=0;i<2;++i)
      #pragma unroll
      for(int j=0;j<8;++j)
        acc[i][j] = __builtin_amdgcn_mfma_f32_16x16x32_bf16(af[i], bfr[j], acc[i][j], 0,0,0);
  }

  // group-norm over DV per row, gate, write bf16
  #pragma unroll
  for(int i=0;i<2;++i){
    #pragma unroll
    for(int r=0;r<4;++r){
      float s1 = 0.f, s2 = 0.f;
      #pragma unroll
      for(int j=0;j<8;++j){ float v = acc[i][j][r]; s1 += v; s2 += v*v; }
      #pragma unroll
      for(int off=1; off<16; off<<=1){ s1 += __shfl_xor(s1, off); s2 += __shfl_xor(s2, off); }
      float mu  = s1 * (1.f/128.f);
      float var = s2 * (1.f/128.f) - mu*mu;
      float inv = rsqrtf(var + 1e-6f);
      int t = w*32 + (i<<4) + ((lane>>4)<<2) + r;
      long mrow = (long)(b*N_ + c*CH_ + t);
      #pragma unroll
      for(int j=0;j<8;++j){
        int dv = (j<<4) + (lane&15);
        float v = (acc[i][j][r] - mu) * inv;
        float g = bf2f(Y[mrow*NCAT_ + 6144 + h*128 + dv]);
        RG[mrow*E_ + h*128 + dv] = f2bf(v * g);
      }
    }
  }
}

// ---------------- launch ----------------
extern "C" void kernel_launch(void* const* d_in, const int* in_sizes, int n_in,
                              void* d_out, int out_size, void* d_ws, size_t ws_size,
                              hipStream_t stream) {
  const float* x  = (const float*)d_in[0];
  const float* Wq = (const float*)d_in[1];
  const float* bq = (const float*)d_in[2];
  const float* Wk = (const float*)d_in[3];
  const float* bk = (const float*)d_in[4];
  const float* Wv = (const float*)d_in[5];
  const float* bv = (const float*)d_in[6];
  const float* Wg = (const float*)d_in[7];
  const float* bg = (const float*)d_in[8];
  const float* Wo = (const float*)d_in[9];
  const float* bo = (const float*)d_in[10];

  char* ws = (char*)d_ws;
  unsigned short* xb   = (unsigned short*)(ws + OFF_XB);
  unsigned short* Wcat = (unsigned short*)(ws + OFF_WCAT);
  unsigned short* Wob  = (unsigned short*)(ws + OFF_WOB);
  float*          bcat = (float*)(ws + OFF_BCAT);
  unsigned short* Y    = (unsigned short*)(ws + OFF_Y);
  unsigned short* Vt   = (unsigned short*)(ws + OFF_VT);
  unsigned short* Scb  = (unsigned short*)(ws + OFF_SCB);
  unsigned short* MS   = (unsigned short*)(ws + OFF_WCAT); // bf16, reuse after GEMM1
  unsigned short* RG   = (unsigned short*)(ws + OFF_XB);   // reuse after GEMM1

  float* outp     = (float*)d_out;
  float* stateOut = outp + (long)M_ * E_;   // 8,388,608

  (void)hipFuncSetAttribute((const void*)k_gemm256,
                            hipFuncAttributeMaxDynamicSharedMemorySize, 131072);
  (void)hipFuncSetAttribute((const void*)k_gemm2,
                            hipFuncAttributeMaxDynamicSharedMemorySize, 98304);

  // fused prep (all casts + bias concat)
  k_castall<<<14340, 256, 0, stream>>>(x, Wq, Wk, Wv, Wg, Wo, bq, bk, bv, bg,
                                       xb, Wcat, Wob, bcat);

  // fused QKVG projection (256^2, 8-phase, cheap decay-baked epilogue)
  k_gemm256<<<512, 512, 131072, stream>>>(xb, Wcat, Y, bcat);

  // fused transpose + per-chunk summary (writes Vt + MS bf16)
  k_chunksumT<<<512, 256, 0, stream>>>(Y, Vt, MS);

  // sequential-over-chunks scan (parallel over state elements)
  k_scan<<<256, 256, 0, stream>>>(MS, Scb, stateOut);

  // retention output (masked QK^T @ V + cross term, group-norm, gate)
  k_ret<<<512, 256, 0, stream>>>(Y, Vt, Scb, RG);

  // output projection (256x128 4-phase)
  k_gemm2<<<256, 512, 98304, stream>>>(RG, Wob, outp, bo);
}